// Round 11
// baseline (365.341 us; speedup 1.0000x reference)
//
#include <hip/hip_runtime.h>
#include <hip/hip_bf16.h>

#define NATOM 128
#define NB    127
#define D0    25
#define D1    50
#define D2    100
#define H1STR 72     // halves; 144 B = 9*16 -> 16B-aligned; A-frag conflict-free
#define MROWS 176    // worst case: 16*ceil(c_t/16) summed = 176 rows (11 tiles)
#define W1H_HALVES (16 * 50 * 32)     // 25600  (K 25 -> 32, zero-padded)
#define W2H_HALVES (16 * 100 * 64)    // 102400 (K 50 -> 64, zero-padded)

typedef _Float16 half8 __attribute__((ext_vector_type(8)));  // 8 fp16 = 4 VGPRs
typedef __attribute__((ext_vector_type(4))) float f32x4;

// tanh(x) = 1 - 2/(exp(2x)+1); exact at +-inf, ~1e-6 rel err.
__device__ __forceinline__ float fast_tanh(float x) {
    float e = __expf(2.0f * x);
    return 1.0f - 2.0f * __builtin_amdgcn_rcpf(e + 1.0f);
}

// ---- one-shot (per launch) fp32 -> fp16 weight repack into d_ws ----------
// W1h[idx][o][k32] (k 25..31 = 0), W2h[idx][o][k64] (k 50..63 = 0).
__global__ void cvt_kernel(const float* __restrict__ W1,
                           const float* __restrict__ W2,
                           unsigned int* __restrict__ ws) {
    const int i = blockIdx.x * 256 + threadIdx.x;   // dword index
    if (i >= (W1H_HALVES + W2H_HALVES) / 2) return;
    float v0, v1;
    if (i < W1H_HALVES / 2) {
        const int s = 2 * i;
        const int row = s >> 5, kk = s & 31;        // row = idx*50 + o
        const float* base = W1 + row * D0;
        v0 = (kk < D0) ? base[kk] : 0.f;
        v1 = (kk + 1 < D0) ? base[kk + 1] : 0.f;
    } else {
        const int s = 2 * i - W1H_HALVES;
        const int row = s >> 6, kk = s & 63;        // row = idx*100 + o
        const float* base = W2 + row * D1;
        v0 = (kk < D1) ? base[kk] : 0.f;
        v1 = (kk + 1 < D1) ? base[kk + 1] : 0.f;
    }
    union { _Float16 h[2]; unsigned int u; } cv;
    cv.h[0] = (_Float16)v0;                         // RNE, range-safe (|W|<0.21)
    cv.h[1] = (_Float16)v1;
    ws[i] = cv.u;
}

__global__ __launch_bounds__(256, 1) void feat_kernel(
    const float* __restrict__ coords,
    const int*   __restrict__ types,
    const float* __restrict__ W0, const float* __restrict__ B0,
    const float* __restrict__ B1, const float* __restrict__ B2,
    const _Float16* __restrict__ W1h, const _Float16* __restrict__ W2h,
    float* __restrict__ out)
{
    // 25344 + 2816 + 5376 + 3200 + 64 = 36800 B -> 4 blocks/CU, 16 waves/CU
    __shared__ __attribute__((aligned(16))) _Float16 H1f[MROWS][H1STR];
    __shared__ float4 E4[MROWS];        // env_a (w=0); zero on pad rows = mask
    __shared__ float  Msw[4][3][112];   // per-wave M slabs
    __shared__ float  P[800];           // W0[4][25] B0[4][25] B1[4][50] B2[4][100]
    __shared__ int    cnt[4][4];        // per-wave type counts (pairs, even lanes)

    const int bn = blockIdx.x;    // b*128 + n
    const int b  = bn >> 7;
    const int n  = bn & 127;
    const int k  = threadIdx.x;   // 0..255
    const int wv = k >> 6;        // wave 0..3
    const int lq = (k >> 4) & 3;  // quad within wave
    const int ln = k & 15;
    const int lane = k & 63;
    const int tn  = types[n];

    // ---- zero LDS (pad rows + cols 50..63 feed MFMA -> must be 0, never NaN)
    {
        const uint2 z2 = {0u, 0u};
        uint2* p1 = (uint2*)&H1f[0][0];
        for (int i = k; i < (MROWS * H1STR) / 4; i += 256) p1[i] = z2;
        const float4 z4 = make_float4(0.f, 0.f, 0.f, 0.f);
        for (int i = k; i < MROWS; i += 256) E4[i] = z4;
    }
    // ---- stage W0/B0/B1/B2 tables for this center type (coalesced, once)
    for (int i = k; i < 800; i += 256) {
        float v;
        if      (i < 100) v = W0[tn * 100 + i];
        else if (i < 200) v = B0[tn * 100 + (i - 100)];
        else if (i < 400) v = B1[tn * 200 + (i - 200)];
        else              v = B2[tn * 400 + (i - 400)];
        P[i] = v;
    }

    // ---- thread = (pair p, half h): p = k>>1 (0..126), h = k&1
    const int p  = k >> 1;
    const int h  = k & 1;
    const bool pv = (k < 254);    // valid pair-thread
    int tj = -1, j0 = 0;
    if (pv) { j0 = p + (p >= n ? 1 : 0); tj = types[j0]; }   // skip self

    // ---- ballot-based type counts + stable ranks over EVEN lanes (pairs)
    const bool rep = pv && (h == 0);
    const unsigned long long bm0 = __ballot(rep && tj == 0);
    const unsigned long long bm1 = __ballot(rep && tj == 1);
    const unsigned long long bm2 = __ballot(rep && tj == 2);
    const unsigned long long bm3 = __ballot(rep && tj == 3);
    if (lane == 0) {
        cnt[wv][0] = __popcll(bm0); cnt[wv][1] = __popcll(bm1);
        cnt[wv][2] = __popcll(bm2); cnt[wv][3] = __popcll(bm3);
    }
    int sameBefore = 0;
    if (pv) {
        const unsigned long long mym =
            (tj == 0) ? bm0 : (tj == 1) ? bm1 : (tj == 2) ? bm2 : bm3;
        // mask up to this pair's even lane -> identical for both halves
        sameBefore = __popcll(mym & ((1ULL << (lane & ~1)) - 1ULL));
    }
    __syncthreads();

    const int c0 = cnt[0][0] + cnt[1][0] + cnt[2][0] + cnt[3][0];
    const int c1 = cnt[0][1] + cnt[1][1] + cnt[2][1] + cnt[3][1];
    const int c2 = cnt[0][2] + cnt[1][2] + cnt[2][2] + cnt[3][2];
    const int c3 = cnt[0][3] + cnt[1][3] + cnt[2][3] + cnt[3][3];
    const int ps1 = (c0 + 15) & ~15;
    const int ps2 = ps1 + ((c1 + 15) & ~15);
    const int ps3 = ps2 + ((c2 + 15) & ~15);

    // ======== phase 1: geometry + layers 0 & 1 per thread (half a pair) ====
    if (pv) {
        const int idx = (tn << 2) | tj;
        const int pst = (tj == 0) ? 0 : (tj == 1) ? ps1 : (tj == 2) ? ps2 : ps3;
        int pre = 0;                       // pairs of my type in earlier waves
        #pragma unroll
        for (int w = 0; w < 4; ++w) if (w < wv) pre += cnt[w][tj];
        const int pr = pst + pre + sameBefore;   // padded row for this pair

        const float cx = coords[(b * NATOM + n) * 3 + 0];
        const float cy = coords[(b * NATOM + n) * 3 + 1];
        const float cz = coords[(b * NATOM + n) * 3 + 2];
        const float dx = cx - coords[(b * NATOM + j0) * 3 + 0];
        const float dy = cy - coords[(b * NATOM + j0) * 3 + 1];
        const float dz = cz - coords[(b * NATOM + j0) * 3 + 2];
        const float d2   = dx * dx + dy * dy + dz * dz;
        const float inv  = rsqrtf(d2);         // 1/d (= env_r)
        const float inv2 = inv * inv;
        if (h == 0) E4[pr] = make_float4(dx * inv2, dy * inv2, dz * inv2, 0.f);

        // layer 0: 1 -> 25 (duplicated across halves: free at wave level)
        const float* w0p = &P[tj * D0];
        const float* b0p = &P[100 + tj * D0];
        float h0[D0];
        #pragma unroll
        for (int o = 0; o < D0; ++o)
            h0[o] = fast_tanh(w0p[o] * inv + b0p[o]);

        // layer 1: this half computes outputs o = h*25 + u, u = 0..24.
        // fp16 weights (half8 loads), fp32 accumulate (v_fma_mix), fp32 h0.
        const _Float16* wrow = W1h + (idx * 50 + h * D0) * 32;
        const float*    b1p  = &P[200 + tj * D1 + h * D0];
        #pragma unroll 5
        for (int u = 0; u < D0; ++u) {
            const half8* r = (const half8*)(wrow + u * 32);  // 64B-aligned
            const half8 r0 = r[0], r1 = r[1], r2 = r[2], r3 = r[3];
            float acc = b1p[u];
            #pragma unroll
            for (int i = 0; i < 8; ++i) acc += (float)r0[i] * h0[i];
            #pragma unroll
            for (int i = 0; i < 8; ++i) acc += (float)r1[i] * h0[8 + i];
            #pragma unroll
            for (int i = 0; i < 8; ++i) acc += (float)r2[i] * h0[16 + i];
            acc += (float)r3[0] * h0[24];
            // residual: o % 25 == u for both halves
            H1f[pr][h * D0 + u] = (_Float16)(fast_tanh(acc) + h0[u]);
        }
    }
    __syncthreads();

    // ======== phase 2: layer 2 via MFMA, single-owner m-tiles ==============
    // D[m][o] = sum_k H1f[m][k] * W2h[idx][o][k]; A: lane&15=m, k=quad*8+j;
    // C/D: col=lane&15 (=o), row=quad*4+r (=m). E=0 on pad rows masks them.
    float Mc[7][3];
    #pragma unroll
    for (int nt = 0; nt < 7; ++nt) { Mc[nt][0] = Mc[nt][1] = Mc[nt][2] = 0.f; }

    int eidx = 0;
    #pragma unroll
    for (int t = 0; t < 4; ++t) {
        const int cnt_t = (t == 0) ? c0 : (t == 1) ? c1 : (t == 2) ? c2 : c3;
        const int ps    = (t == 0) ? 0  : (t == 1) ? ps1 : (t == 2) ? ps2 : ps3;
        const int idx   = (tn << 2) | t;
        const int mtiles = (cnt_t + 15) >> 4;
        for (int mt = 0; mt < mtiles; ++mt, ++eidx) {
            if ((eidx & 3) != wv) continue;
            const int mb = ps + mt * 16;

            const float4 e0 = E4[mb + lq * 4 + 0];
            const float4 e1 = E4[mb + lq * 4 + 1];
            const float4 e2 = E4[mb + lq * 4 + 2];
            const float4 e3 = E4[mb + lq * 4 + 3];

            const _Float16* arow = &H1f[mb + ln][0];
            const half8 af0 = *(const half8*)(arow + lq * 8);        // k<32
            const half8 af1 = *(const half8*)(arow + 32 + lq * 8);   // K-pad=0
            #pragma unroll
            for (int nt = 0; nt < 7; ++nt) {
                const int o  = nt * 16 + ln;
                const bool ov = (o < D2);
                const int oc = ov ? o : (D2 - 1);
                const _Float16* wr = W2h + (idx * 100 + oc) * 64;
                const half8 bf0 = *(const half8*)(wr + lq * 8);
                const half8 bf1 = *(const half8*)(wr + 32 + lq * 8);
                f32x4 d = {0.f, 0.f, 0.f, 0.f};
                d = __builtin_amdgcn_mfma_f32_16x16x32_f16(af0, bf0, d, 0, 0, 0);
                d = __builtin_amdgcn_mfma_f32_16x16x32_f16(af1, bf1, d, 0, 0, 0);
                const float b2n = P[400 + t * D2 + oc];
                const int rres = oc % D1;
                const int mq = mb + lq * 4;
                const float g0 = fast_tanh(d[0] + b2n) + (float)H1f[mq + 0][rres];
                const float g1 = fast_tanh(d[1] + b2n) + (float)H1f[mq + 1][rres];
                const float g2 = fast_tanh(d[2] + b2n) + (float)H1f[mq + 2][rres];
                const float g3 = fast_tanh(d[3] + b2n) + (float)H1f[mq + 3][rres];
                Mc[nt][0] += e0.x * g0 + e1.x * g1 + e2.x * g2 + e3.x * g3;
                Mc[nt][1] += e0.y * g0 + e1.y * g1 + e2.y * g2 + e3.y * g3;
                Mc[nt][2] += e0.z * g0 + e1.z * g1 + e2.z * g2 + e3.z * g3;
            }
        }
    }

    // ---- fold quads, write this wave's slab (all 112 columns covered)
    #pragma unroll
    for (int nt = 0; nt < 7; ++nt) {
        float m0 = Mc[nt][0], m1 = Mc[nt][1], m2 = Mc[nt][2];
        m0 += __shfl_xor(m0, 16, 64); m1 += __shfl_xor(m1, 16, 64);
        m2 += __shfl_xor(m2, 16, 64);
        m0 += __shfl_xor(m0, 32, 64); m1 += __shfl_xor(m1, 32, 64);
        m2 += __shfl_xor(m2, 32, 64);
        if (lq == 0) {
            const int o = nt * 16 + ln;
            Msw[wv][0][o] = m0; Msw[wv][1][o] = m1; Msw[wv][2][o] = m2;
        }
    }
    __syncthreads();

    // ======== phase 3: out[m][a] = sum_c M[c][m] * M[c][a], a < 4 ==========
    if (k < D2) {
        const float m0 = Msw[0][0][k] + Msw[1][0][k] + Msw[2][0][k] + Msw[3][0][k];
        const float m1 = Msw[0][1][k] + Msw[1][1][k] + Msw[2][1][k] + Msw[3][1][k];
        const float m2 = Msw[0][2][k] + Msw[1][2][k] + Msw[2][2][k] + Msw[3][2][k];
        float4 o4;
        #pragma unroll
        for (int a = 0; a < 4; ++a) {
            const float a0 = Msw[0][0][a] + Msw[1][0][a] + Msw[2][0][a] + Msw[3][0][a];
            const float a1 = Msw[0][1][a] + Msw[1][1][a] + Msw[2][1][a] + Msw[3][1][a];
            const float a2 = Msw[0][2][a] + Msw[1][2][a] + Msw[2][2][a] + Msw[3][2][a];
            const float v = m0 * a0 + m1 * a1 + m2 * a2;
            if (a == 0) o4.x = v; else if (a == 1) o4.y = v;
            else if (a == 2) o4.z = v; else o4.w = v;
        }
        reinterpret_cast<float4*>(out)[bn * D2 + k] = o4;   // 16B-aligned
    }
}

extern "C" void kernel_launch(void* const* d_in, const int* in_sizes, int n_in,
                              void* d_out, int out_size, void* d_ws, size_t ws_size,
                              hipStream_t stream) {
    (void)in_sizes; (void)n_in; (void)out_size; (void)ws_size;
    const float* coords = (const float*)d_in[0];
    const int*   types  = (const int*)  d_in[1];
    const float* W0 = (const float*)d_in[2];
    const float* B0 = (const float*)d_in[3];
    const float* W1 = (const float*)d_in[4];
    const float* B1 = (const float*)d_in[5];
    const float* W2 = (const float*)d_in[6];
    const float* B2 = (const float*)d_in[7];
    float* out = (float*)d_out;

    _Float16* W1h = (_Float16*)d_ws;                 // 25600 halves
    _Float16* W2h = (_Float16*)d_ws + W1H_HALVES;    // 102400 halves

    const int cvt_dwords = (W1H_HALVES + W2H_HALVES) / 2;      // 64000
    cvt_kernel<<<(cvt_dwords + 255) / 256, 256, 0, stream>>>(
        W1, W2, (unsigned int*)d_ws);

    feat_kernel<<<64 * NATOM, 256, 0, stream>>>(
        coords, types, W0, B0, B1, B2, W1h, W2h, out);
}

// Round 12
// 221.129 us; speedup vs baseline: 1.6522x; 1.6522x over previous
//
#include <hip/hip_runtime.h>
#include <hip/hip_bf16.h>

#define NATOM 128
#define NB    127
#define D0    25
#define D1    50
#define D2    100
#define H0STR 40     // halves; 80 B rows: 16B-aligned, A-frag pattern 2-way = free
#define H1STR 72     // halves; 144 B rows: 16B-aligned, A-frag pattern 2-way = free
#define MROWS 176    // worst case: sum 16*ceil(c_t/16) = 176 rows (11 tiles)
#define W1H_HALVES (16 * 50 * 32)     // 25600  (K 25 -> 32, zero-padded)
#define W2H_HALVES (16 * 100 * 64)    // 102400 (K 50 -> 64, zero-padded)

typedef _Float16 half8 __attribute__((ext_vector_type(8)));  // 8 fp16 = 4 VGPRs
typedef __attribute__((ext_vector_type(4))) float f32x4;

// tanh(x) = 1 - 2/(exp(2x)+1); exact at +-inf, ~1e-6 rel err.
__device__ __forceinline__ float fast_tanh(float x) {
    float e = __expf(2.0f * x);
    return 1.0f - 2.0f * __builtin_amdgcn_rcpf(e + 1.0f);
}

// ---- one-shot (per launch) fp32 -> fp16 weight repack into d_ws ----------
// W1h[idx][o][k32] (k 25..31 = 0), W2h[idx][o][k64] (k 50..63 = 0).
// d_ws is re-poisoned before every timed launch, so this runs every call.
__global__ void cvt_kernel(const float* __restrict__ W1,
                           const float* __restrict__ W2,
                           unsigned int* __restrict__ ws) {
    const int i = blockIdx.x * 256 + threadIdx.x;   // dword index
    if (i >= (W1H_HALVES + W2H_HALVES) / 2) return;
    float v0, v1;
    if (i < W1H_HALVES / 2) {
        const int s = 2 * i;
        const int row = s >> 5, kk = s & 31;        // row = idx*50 + o
        const float* base = W1 + row * D0;
        v0 = (kk < D0) ? base[kk] : 0.f;
        v1 = (kk + 1 < D0) ? base[kk + 1] : 0.f;
    } else {
        const int s = 2 * i - W1H_HALVES;
        const int row = s >> 6, kk = s & 63;        // row = idx*100 + o
        const float* base = W2 + row * D1;
        v0 = (kk < D1) ? base[kk] : 0.f;
        v1 = (kk + 1 < D1) ? base[kk + 1] : 0.f;
    }
    union { _Float16 h[2]; unsigned int u; } cv;
    cv.h[0] = (_Float16)v0;                         // RNE, range-safe (|W|<0.21)
    cv.h[1] = (_Float16)v1;
    ws[i] = cv.u;
}

__global__ __launch_bounds__(256, 1) void feat_kernel(
    const float* __restrict__ coords,
    const int*   __restrict__ types,
    const float* __restrict__ W0, const float* __restrict__ B0,
    const float* __restrict__ B1, const float* __restrict__ B2,
    const _Float16* __restrict__ W1h, const _Float16* __restrict__ W2h,
    float* __restrict__ out)
{
    // 25344 + 14080 + 2816 + 1344 + 3200 + 32 = 46816 B -> 3 blocks/CU
    __shared__ __attribute__((aligned(16))) _Float16 H1f[MROWS][H1STR];
    __shared__ __attribute__((aligned(16))) _Float16 H0f[MROWS][H0STR];
    __shared__ float4 E4[MROWS];        // env_a (w=0); zero on pad rows = mask
    __shared__ float  Ms[3][112];
    __shared__ float  P[800];           // W0[4][25] B0[4][25] B1[4][50] B2[4][100]
    __shared__ int    cnt[2][4];        // per-wave type counts (waves 0,1)

    const int bn = blockIdx.x;    // b*128 + n
    const int b  = bn >> 7;
    const int n  = bn & 127;
    const int k  = threadIdx.x;   // 0..255
    const int wv = k >> 6;        // wave 0..3
    const int lq = (k >> 4) & 3;  // quad within wave
    const int ln = k & 15;
    const int lane = k & 63;
    const int tn  = types[n];

    // ---- zero LDS (pad rows/cols feed MFMA -> must be 0, never NaN)
    {
        const uint2 z2 = {0u, 0u};
        uint2* p1 = (uint2*)&H1f[0][0];
        for (int i = k; i < (MROWS * H1STR) / 4; i += 256) p1[i] = z2;
        uint2* p0 = (uint2*)&H0f[0][0];
        for (int i = k; i < (MROWS * H0STR) / 4; i += 256) p0[i] = z2;
        const float4 z4 = make_float4(0.f, 0.f, 0.f, 0.f);
        for (int i = k; i < MROWS; i += 256) E4[i] = z4;
    }
    // ---- stage W0/B0/B1/B2 tables for this center type (coalesced, once)
    for (int i = k; i < 800; i += 256) {
        float v;
        if      (i < 100) v = W0[tn * 100 + i];
        else if (i < 200) v = B0[tn * 100 + (i - 100)];
        else if (i < 400) v = B1[tn * 200 + (i - 200)];
        else              v = B2[tn * 400 + (i - 400)];
        P[i] = v;
    }

    // ---- ballot-based type counts + stable ranks (pairs live in waves 0,1)
    int tj = -1, j0 = 0;
    if (k < NB) { j0 = k + (k >= n ? 1 : 0); tj = types[j0]; }   // skip self
    const unsigned long long bm0 = __ballot(tj == 0);
    const unsigned long long bm1 = __ballot(tj == 1);
    const unsigned long long bm2 = __ballot(tj == 2);
    const unsigned long long bm3 = __ballot(tj == 3);
    if (lane == 0 && wv < 2) {
        cnt[wv][0] = __popcll(bm0); cnt[wv][1] = __popcll(bm1);
        cnt[wv][2] = __popcll(bm2); cnt[wv][3] = __popcll(bm3);
    }
    int sameBefore = 0;
    if (k < NB) {
        const unsigned long long mym =
            (tj == 0) ? bm0 : (tj == 1) ? bm1 : (tj == 2) ? bm2 : bm3;
        sameBefore = __popcll(mym & ((1ULL << lane) - 1ULL));
    }
    __syncthreads();

    const int c0 = cnt[0][0] + cnt[1][0];
    const int c1 = cnt[0][1] + cnt[1][1];
    const int c2 = cnt[0][2] + cnt[1][2];
    const int c3 = cnt[0][3] + cnt[1][3];
    const int ps1 = (c0 + 15) & ~15;
    const int ps2 = ps1 + ((c1 + 15) & ~15);
    const int ps3 = ps2 + ((c2 + 15) & ~15);

    // ======== phase 1: geometry + layer 0 (thread k -> its own padded row) ==
    if (k < NB) {
        const int pst = (tj == 0) ? 0 : (tj == 1) ? ps1 : (tj == 2) ? ps2 : ps3;
        const int pr  = pst + sameBefore + ((wv == 1) ? cnt[0][tj] : 0);

        const float cx = coords[(b * NATOM + n) * 3 + 0];
        const float cy = coords[(b * NATOM + n) * 3 + 1];
        const float cz = coords[(b * NATOM + n) * 3 + 2];
        const float dx = cx - coords[(b * NATOM + j0) * 3 + 0];
        const float dy = cy - coords[(b * NATOM + j0) * 3 + 1];
        const float dz = cz - coords[(b * NATOM + j0) * 3 + 2];
        const float d2   = dx * dx + dy * dy + dz * dz;
        const float inv  = rsqrtf(d2);         // 1/d (= env_r)
        const float inv2 = inv * inv;
        E4[pr] = make_float4(dx * inv2, dy * inv2, dz * inv2, 0.f);

        // layer 0: 1 -> 25 from LDS tables (<=4-way divergent LDS reads)
        const float* w  = &P[tj * D0];
        const float* bb = &P[100 + tj * D0];
        float h0[D0];
        #pragma unroll
        for (int o = 0; o < D0; ++o)
            h0[o] = fast_tanh(w[o] * inv + bb[o]);

        // store h0 fp16 (cols 25..31 stay 0 = K-pad for the 16x16x32 MFMA)
        unsigned int* dst = (unsigned int*)&H0f[pr][0];
        #pragma unroll
        for (int o = 0; o < D0 - 1; o += 2) {
            union { _Float16 h[2]; unsigned int u; } cv;
            cv.h[0] = (_Float16)h0[o];
            cv.h[1] = (_Float16)h0[o + 1];
            dst[o >> 1] = cv.u;
        }
        {
            union { _Float16 h[2]; unsigned int u; } cl;
            cl.h[0] = (_Float16)h0[24];
            cl.h[1] = (_Float16)0.f;
            dst[12] = cl.u;
        }
    }
    __syncthreads();

    // ======== phase 2a: layer 1 via MFMA (25 -> 50), K padded to 32 ========
    // Wave wv owns N-tile o1 = wv*16+ln, loops all 4 types (balanced MFMA
    // count; wave 3 has only 2 valid cols but equal instruction count).
    // A[m=ln][k=lq*8+j] from H0f (ds_read_b128); B[k][o1] = W1h row (half8,
    // hoisted out of the mt loop). C/D: col=ln (=o1), row=lq*4+r (=m).
    {
        const int o1   = wv * 16 + ln;         // 0..63
        const bool ov1 = (o1 < D1);
        const int o1c  = ov1 ? o1 : 0;         // clamp: pad lanes load row 0
        const int rres1 = (o1 < D0) ? o1 : o1 - D0;   // o1 % 25
        #pragma unroll
        for (int t = 0; t < 4; ++t) {
            const int cnt_t = (t == 0) ? c0 : (t == 1) ? c1 : (t == 2) ? c2 : c3;
            if (cnt_t == 0) continue;
            const int ps  = (t == 0) ? 0 : (t == 1) ? ps1 : (t == 2) ? ps2 : ps3;
            const int idx = (tn << 2) | t;
            const half8 bf =
                *(const half8*)(W1h + (idx * 50 + o1c) * 32 + lq * 8);
            const float b1v = ov1 ? P[200 + t * D1 + o1] : 0.f;
            const int mtiles = (cnt_t + 15) >> 4;
            for (int mt = 0; mt < mtiles; ++mt) {
                const int mb = ps + mt * 16;
                const half8 af = *(const half8*)(&H0f[mb + ln][lq * 8]);
                f32x4 d = {0.f, 0.f, 0.f, 0.f};
                d = __builtin_amdgcn_mfma_f32_16x16x32_f16(af, bf, d, 0, 0, 0);
                if (ov1) {                      // never touch cols >= 50 of H1f
                    #pragma unroll
                    for (int r = 0; r < 4; ++r) {
                        const int m = mb + lq * 4 + r;
                        const float h1v =
                            fast_tanh(d[r] + b1v) + (float)H0f[m][rres1];
                        H1f[m][o1] = (_Float16)h1v;
                    }
                }
            }
        }
    }
    __syncthreads();

    // ======== phase 2b: layer 2 via MFMA (50 -> 100) + fused M-reduce ======
    // B-frags hoisted out of the mt loop (the r11 regression was inverting
    // this). E=0 on pad rows masks garbage; Ms cols 100..111 never read.
    for (int nt = wv; nt < 7; nt += 4) {
        const int o  = nt * 16 + ln;           // output neuron
        const bool ov = (o < D2);
        const int oc = ov ? o : (D2 - 1);
        const int rres = oc % D1;              // residual column
        float Mc0 = 0.f, Mc1 = 0.f, Mc2 = 0.f;
        #pragma unroll
        for (int t = 0; t < 4; ++t) {
            const int cnt_t = (t == 0) ? c0 : (t == 1) ? c1 : (t == 2) ? c2 : c3;
            if (cnt_t == 0) continue;
            const int ps  = (t == 0) ? 0 : (t == 1) ? ps1 : (t == 2) ? ps2 : ps3;
            const int idx = (tn << 2) | t;
            const _Float16* wr = W2h + (idx * 100 + oc) * 64;
            const half8 bf0 = *(const half8*)(wr + lq * 8);        // k<32
            const half8 bf1 = *(const half8*)(wr + 32 + lq * 8);   // K-pad=0
            const float b2n = P[400 + t * D2 + oc];
            const int mtiles = (cnt_t + 15) >> 4;
            for (int mt = 0; mt < mtiles; ++mt) {
                const int mb = ps + mt * 16;
                const _Float16* arow = &H1f[mb + ln][0];
                const half8 af0 = *(const half8*)(arow + lq * 8);
                const half8 af1 = *(const half8*)(arow + 32 + lq * 8);
                f32x4 d = {0.f, 0.f, 0.f, 0.f};
                d = __builtin_amdgcn_mfma_f32_16x16x32_f16(af0, bf0, d, 0, 0, 0);
                d = __builtin_amdgcn_mfma_f32_16x16x32_f16(af1, bf1, d, 0, 0, 0);
                #pragma unroll
                for (int r = 0; r < 4; ++r) {          // C/D: row = quad*4+r
                    const int m = mb + lq * 4 + r;
                    const float4 e = E4[m];            // 0 on pad rows = mask
                    const float g = fast_tanh(d[r] + b2n) + (float)H1f[m][rres];
                    Mc0 += e.x * g; Mc1 += e.y * g; Mc2 += e.z * g;
                }
            }
        }
        // reduce across the 4 quads (rows); lanes differ only in lq
        Mc0 += __shfl_xor(Mc0, 16, 64); Mc1 += __shfl_xor(Mc1, 16, 64);
        Mc2 += __shfl_xor(Mc2, 16, 64);
        Mc0 += __shfl_xor(Mc0, 32, 64); Mc1 += __shfl_xor(Mc1, 32, 64);
        Mc2 += __shfl_xor(Mc2, 32, 64);
        if (lq == 0 && ov) {
            Ms[0][o] = Mc0; Ms[1][o] = Mc1; Ms[2][o] = Mc2;
        }
    }
    __syncthreads();

    // ======== phase 3: out[m][a] = sum_c M[c][m] * M[c][a], a < 4 ==========
    if (k < D2) {
        const float m0 = Ms[0][k], m1 = Ms[1][k], m2 = Ms[2][k];
        float4 o4;
        o4.x = m0 * Ms[0][0] + m1 * Ms[1][0] + m2 * Ms[2][0];
        o4.y = m0 * Ms[0][1] + m1 * Ms[1][1] + m2 * Ms[2][1];
        o4.z = m0 * Ms[0][2] + m1 * Ms[1][2] + m2 * Ms[2][2];
        o4.w = m0 * Ms[0][3] + m1 * Ms[1][3] + m2 * Ms[2][3];
        reinterpret_cast<float4*>(out)[bn * D2 + k] = o4;   // 16B-aligned
    }
}

extern "C" void kernel_launch(void* const* d_in, const int* in_sizes, int n_in,
                              void* d_out, int out_size, void* d_ws, size_t ws_size,
                              hipStream_t stream) {
    (void)in_sizes; (void)n_in; (void)out_size; (void)ws_size;
    const float* coords = (const float*)d_in[0];
    const int*   types  = (const int*)  d_in[1];
    const float* W0 = (const float*)d_in[2];
    const float* B0 = (const float*)d_in[3];
    const float* W1 = (const float*)d_in[4];
    const float* B1 = (const float*)d_in[5];
    const float* W2 = (const float*)d_in[6];
    const float* B2 = (const float*)d_in[7];
    float* out = (float*)d_out;

    _Float16* W1h = (_Float16*)d_ws;                 // 25600 halves
    _Float16* W2h = (_Float16*)d_ws + W1H_HALVES;    // 102400 halves

    const int cvt_dwords = (W1H_HALVES + W2H_HALVES) / 2;      // 64000
    cvt_kernel<<<(cvt_dwords + 255) / 256, 256, 0, stream>>>(
        W1, W2, (unsigned int*)d_ws);

    feat_kernel<<<64 * NATOM, 256, 0, stream>>>(
        coords, types, W0, B0, B1, B2, W1h, W2h, out);
}

// Round 13
// 191.914 us; speedup vs baseline: 1.9037x; 1.1522x over previous
//
#include <hip/hip_runtime.h>
#include <hip/hip_bf16.h>

#define NATOM 128
#define NB    127
#define D0    25
#define D1    50
#define D2    100
#define H0STR 32     // halves; 64 B rows; b128 A-frag reads saturate regardless
#define H1STR 72     // halves; 144 B rows: 16B-aligned, A-frag pattern conflict-light
#define MROWS 176    // worst case: sum 16*ceil(c_t/16) = 176 rows (11 tiles)
#define ESTR  178    // fp32 plane stride
#define W1H_HALVES (16 * 50 * 32)     // 25600  (K 25 -> 32, zero-padded)
#define W2H_HALVES (16 * 100 * 64)    // 102400 (K 50 -> 64, zero-padded)

typedef _Float16 half8 __attribute__((ext_vector_type(8)));  // 8 fp16 = 4 VGPRs
typedef __attribute__((ext_vector_type(4))) float f32x4;

// tanh(x) = 1 - 2/(exp(2x)+1); exact at +-inf, ~1e-6 rel err.
__device__ __forceinline__ float fast_tanh(float x) {
    float e = __expf(2.0f * x);
    return 1.0f - 2.0f * __builtin_amdgcn_rcpf(e + 1.0f);
}

// ---- one-shot (per launch) fp32 -> fp16 weight repack into d_ws ----------
// W1h[idx][o][k32] (k 25..31 = 0), W2h[idx][o][k64] (k 50..63 = 0).
__global__ void cvt_kernel(const float* __restrict__ W1,
                           const float* __restrict__ W2,
                           unsigned int* __restrict__ ws) {
    const int i = blockIdx.x * 256 + threadIdx.x;   // dword index
    if (i >= (W1H_HALVES + W2H_HALVES) / 2) return;
    float v0, v1;
    if (i < W1H_HALVES / 2) {
        const int s = 2 * i;
        const int row = s >> 5, kk = s & 31;        // row = idx*50 + o
        const float* base = W1 + row * D0;
        v0 = (kk < D0) ? base[kk] : 0.f;
        v1 = (kk + 1 < D0) ? base[kk + 1] : 0.f;
    } else {
        const int s = 2 * i - W1H_HALVES;
        const int row = s >> 6, kk = s & 63;        // row = idx*100 + o
        const float* base = W2 + row * D1;
        v0 = (kk < D1) ? base[kk] : 0.f;
        v1 = (kk + 1 < D1) ? base[kk + 1] : 0.f;
    }
    union { _Float16 h[2]; unsigned int u; } cv;
    cv.h[0] = (_Float16)v0;                         // RNE, range-safe (|W|<0.21)
    cv.h[1] = (_Float16)v1;
    ws[i] = cv.u;
}

__global__ __launch_bounds__(256, 1) void feat_kernel(
    const float* __restrict__ coords,
    const int*   __restrict__ types,
    const float* __restrict__ W0, const float* __restrict__ B0,
    const float* __restrict__ B1, const float* __restrict__ B2,
    const _Float16* __restrict__ W1h, const _Float16* __restrict__ W2h,
    float* __restrict__ out)
{
    // 25344 + 11264 + 2136 + 400 + 800 + 32 = 39976 B -> 4 blocks/CU, 16 waves
    __shared__ __attribute__((aligned(16))) _Float16 H1f[MROWS][H1STR];
    // H0f's last read is before the 2a->2b barrier; Ms's first write is after
    // -> lifetimes provably disjoint, union saves 1344 B.
    __shared__ union __attribute__((aligned(16))) {
        _Float16 H0f[MROWS][H0STR];
        float    Ms[3][112];
    } u;
    __shared__ float Ep[3][ESTR];       // env_a planes; zero on pad rows = mask
    __shared__ _Float16 PB1[4][D1];     // fp16 biases (rounding <= 2e-4)
    __shared__ _Float16 PB2[4][D2];
    __shared__ int cnt[2][4];           // per-wave type counts (waves 0,1)

    const int bn = blockIdx.x;    // b*128 + n
    const int b  = bn >> 7;
    const int n  = bn & 127;
    const int k  = threadIdx.x;   // 0..255
    const int wv = k >> 6;        // wave 0..3
    const int lq = (k >> 4) & 3;  // quad within wave
    const int ln = k & 15;
    const int lane = k & 63;
    const int tn  = types[n];

    // ---- zero LDS (pad rows/cols feed MFMA -> must be 0, never NaN)
    {
        const uint2 z2 = {0u, 0u};
        uint2* p1 = (uint2*)&H1f[0][0];
        for (int i = k; i < (MROWS * H1STR) / 4; i += 256) p1[i] = z2;
        uint2* p0 = (uint2*)&u.H0f[0][0];
        for (int i = k; i < (MROWS * H0STR) / 4; i += 256) p0[i] = z2;
        float* ez = &Ep[0][0];
        for (int i = k; i < 3 * ESTR; i += 256) ez[i] = 0.f;
    }
    // ---- stage fp16 bias tables for this center type (coalesced, once)
    for (int i = k; i < 600; i += 256) {
        if (i < 200) PB1[0][i] = (_Float16)B1[tn * 200 + i];          // flat
        else         PB2[0][i - 200] = (_Float16)B2[tn * 400 + (i - 200)];
    }

    // ---- ballot-based type counts + stable ranks (pairs live in waves 0,1)
    int tj = -1, j0 = 0;
    if (k < NB) { j0 = k + (k >= n ? 1 : 0); tj = types[j0]; }   // skip self
    const unsigned long long bm0 = __ballot(tj == 0);
    const unsigned long long bm1 = __ballot(tj == 1);
    const unsigned long long bm2 = __ballot(tj == 2);
    const unsigned long long bm3 = __ballot(tj == 3);
    if (lane == 0 && wv < 2) {
        cnt[wv][0] = __popcll(bm0); cnt[wv][1] = __popcll(bm1);
        cnt[wv][2] = __popcll(bm2); cnt[wv][3] = __popcll(bm3);
    }
    int sameBefore = 0;
    if (k < NB) {
        const unsigned long long mym =
            (tj == 0) ? bm0 : (tj == 1) ? bm1 : (tj == 2) ? bm2 : bm3;
        sameBefore = __popcll(mym & ((1ULL << lane) - 1ULL));
    }
    __syncthreads();

    const int c0 = cnt[0][0] + cnt[1][0];
    const int c1 = cnt[0][1] + cnt[1][1];
    const int c2 = cnt[0][2] + cnt[1][2];
    const int c3 = cnt[0][3] + cnt[1][3];
    const int ps1 = (c0 + 15) & ~15;
    const int ps2 = ps1 + ((c1 + 15) & ~15);
    const int ps3 = ps2 + ((c2 + 15) & ~15);

    // ======== phase 1: geometry + layer 0 (thread k -> its own padded row) ==
    if (k < NB) {
        const int idx = (tn << 2) | tj;
        const int pst = (tj == 0) ? 0 : (tj == 1) ? ps1 : (tj == 2) ? ps2 : ps3;
        const int pr  = pst + sameBefore + ((wv == 1) ? cnt[0][tj] : 0);

        const float cx = coords[(b * NATOM + n) * 3 + 0];
        const float cy = coords[(b * NATOM + n) * 3 + 1];
        const float cz = coords[(b * NATOM + n) * 3 + 2];
        const float dx = cx - coords[(b * NATOM + j0) * 3 + 0];
        const float dy = cy - coords[(b * NATOM + j0) * 3 + 1];
        const float dz = cz - coords[(b * NATOM + j0) * 3 + 2];
        const float d2   = dx * dx + dy * dy + dz * dz;
        const float inv  = rsqrtf(d2);         // 1/d (= env_r)
        const float inv2 = inv * inv;
        Ep[0][pr] = dx * inv2;                 // stride-1 across lanes
        Ep[1][pr] = dy * inv2;
        Ep[2][pr] = dz * inv2;

        // layer 0: 1 -> 25 (global reads, <=4-way divergent, L1-hot — r8 mode)
        const float* w  = W0 + idx * D0;
        const float* bb = B0 + idx * D0;
        float h0[D0];
        #pragma unroll
        for (int o = 0; o < D0; ++o)
            h0[o] = fast_tanh(w[o] * inv + bb[o]);

        // store h0 fp16 (cols 25..31 stay 0 = K-pad for the 16x16x32 MFMA)
        unsigned int* dst = (unsigned int*)&u.H0f[pr][0];
        #pragma unroll
        for (int o = 0; o < D0 - 1; o += 2) {
            union { _Float16 h[2]; unsigned int v; } cv;
            cv.h[0] = (_Float16)h0[o];
            cv.h[1] = (_Float16)h0[o + 1];
            dst[o >> 1] = cv.v;
        }
        {
            union { _Float16 h[2]; unsigned int v; } cl;
            cl.h[0] = (_Float16)h0[24];
            cl.h[1] = (_Float16)0.f;
            dst[12] = cl.v;
        }
    }
    __syncthreads();

    // ======== phase 2a: layer 1 via MFMA (25 -> 50), K padded to 32 ========
    // Wave wv owns N-tile o1 = wv*16+ln, loops all 4 types. A[m=ln][k=lq*8+j]
    // from H0f (ds_read_b128); B[k][o1] = W1h row (half8, hoisted). Bias is
    // the MFMA C-operand. C/D: col=ln (=o1), row=lq*4+r (=m).
    {
        const int o1   = wv * 16 + ln;         // 0..63
        const bool ov1 = (o1 < D1);
        const int o1c  = ov1 ? o1 : 0;         // clamp: pad lanes load row 0
        const int rres1 = (o1 < D0) ? o1 : o1 - D0;   // o1 % 25
        #pragma unroll
        for (int t = 0; t < 4; ++t) {
            const int cnt_t = (t == 0) ? c0 : (t == 1) ? c1 : (t == 2) ? c2 : c3;
            if (cnt_t == 0) continue;
            const int ps  = (t == 0) ? 0 : (t == 1) ? ps1 : (t == 2) ? ps2 : ps3;
            const int idx = (tn << 2) | t;
            const half8 bf =
                *(const half8*)(W1h + (idx * 50 + o1c) * 32 + lq * 8);
            const float b1v = ov1 ? (float)PB1[t][o1c] : 0.f;
            const int mtiles = (cnt_t + 15) >> 4;
            for (int mt = 0; mt < mtiles; ++mt) {
                const int mb = ps + mt * 16;
                const half8 af = *(const half8*)(&u.H0f[mb + ln][lq * 8]);
                f32x4 d = {b1v, b1v, b1v, b1v};        // bias as C-operand
                d = __builtin_amdgcn_mfma_f32_16x16x32_f16(af, bf, d, 0, 0, 0);
                if (ov1) {                      // never touch cols >= 50 of H1f
                    #pragma unroll
                    for (int r = 0; r < 4; ++r) {
                        const int m = mb + lq * 4 + r;
                        const float h1v =
                            fast_tanh(d[r]) + (float)u.H0f[m][rres1];
                        H1f[m][o1] = (_Float16)h1v;
                    }
                }
            }
        }
    }
    __syncthreads();
    // ---- from here on, u is Ms; H0f is dead (all reads were pre-barrier)

    // ======== phase 2b: layer 2 via MFMA (50 -> 100) + fused M-reduce ======
    for (int nt = wv; nt < 7; nt += 4) {
        const int o  = nt * 16 + ln;           // output neuron
        const bool ov = (o < D2);
        const int oc = ov ? o : (D2 - 1);
        const int rres = oc % D1;              // residual column
        float Mc0 = 0.f, Mc1 = 0.f, Mc2 = 0.f;
        #pragma unroll
        for (int t = 0; t < 4; ++t) {
            const int cnt_t = (t == 0) ? c0 : (t == 1) ? c1 : (t == 2) ? c2 : c3;
            if (cnt_t == 0) continue;
            const int ps  = (t == 0) ? 0 : (t == 1) ? ps1 : (t == 2) ? ps2 : ps3;
            const int idx = (tn << 2) | t;
            const _Float16* wr = W2h + (idx * 100 + oc) * 64;
            const half8 bf0 = *(const half8*)(wr + lq * 8);        // k<32
            const half8 bf1 = *(const half8*)(wr + 32 + lq * 8);   // K-pad=0
            const float b2n = (float)PB2[t][oc];
            const int mtiles = (cnt_t + 15) >> 4;
            for (int mt = 0; mt < mtiles; ++mt) {
                const int mb = ps + mt * 16;
                const _Float16* arow = &H1f[mb + ln][0];
                const half8 af0 = *(const half8*)(arow + lq * 8);
                const half8 af1 = *(const half8*)(arow + 32 + lq * 8);
                f32x4 d = {b2n, b2n, b2n, b2n};        // bias as C-operand
                d = __builtin_amdgcn_mfma_f32_16x16x32_f16(af0, bf0, d, 0, 0, 0);
                d = __builtin_amdgcn_mfma_f32_16x16x32_f16(af1, bf1, d, 0, 0, 0);
                const int mq = mb + lq * 4;
                #pragma unroll
                for (int r = 0; r < 4; ++r) {          // C/D: row = quad*4+r
                    const int m = mq + r;
                    // Ep = 0 on pad rows masks garbage
                    const float g = fast_tanh(d[r]) + (float)H1f[m][rres];
                    Mc0 += Ep[0][m] * g;
                    Mc1 += Ep[1][m] * g;
                    Mc2 += Ep[2][m] * g;
                }
            }
        }
        // reduce across the 4 quads (rows); lanes differ only in lq
        Mc0 += __shfl_xor(Mc0, 16, 64); Mc1 += __shfl_xor(Mc1, 16, 64);
        Mc2 += __shfl_xor(Mc2, 16, 64);
        Mc0 += __shfl_xor(Mc0, 32, 64); Mc1 += __shfl_xor(Mc1, 32, 64);
        Mc2 += __shfl_xor(Mc2, 32, 64);
        if (lq == 0 && ov) {
            u.Ms[0][o] = Mc0; u.Ms[1][o] = Mc1; u.Ms[2][o] = Mc2;
        }
    }
    __syncthreads();

    // ======== phase 3: out[m][a] = sum_c M[c][m] * M[c][a], a < 4 ==========
    if (k < D2) {
        const float m0 = u.Ms[0][k], m1 = u.Ms[1][k], m2 = u.Ms[2][k];
        float4 o4;
        o4.x = m0 * u.Ms[0][0] + m1 * u.Ms[1][0] + m2 * u.Ms[2][0];
        o4.y = m0 * u.Ms[0][1] + m1 * u.Ms[1][1] + m2 * u.Ms[2][1];
        o4.z = m0 * u.Ms[0][2] + m1 * u.Ms[1][2] + m2 * u.Ms[2][2];
        o4.w = m0 * u.Ms[0][3] + m1 * u.Ms[1][3] + m2 * u.Ms[2][3];
        reinterpret_cast<float4*>(out)[bn * D2 + k] = o4;   // 16B-aligned
    }
}

extern "C" void kernel_launch(void* const* d_in, const int* in_sizes, int n_in,
                              void* d_out, int out_size, void* d_ws, size_t ws_size,
                              hipStream_t stream) {
    (void)in_sizes; (void)n_in; (void)out_size; (void)ws_size;
    const float* coords = (const float*)d_in[0];
    const int*   types  = (const int*)  d_in[1];
    const float* W0 = (const float*)d_in[2];
    const float* B0 = (const float*)d_in[3];
    const float* W1 = (const float*)d_in[4];
    const float* B1 = (const float*)d_in[5];
    const float* W2 = (const float*)d_in[6];
    const float* B2 = (const float*)d_in[7];
    float* out = (float*)d_out;

    _Float16* W1h = (_Float16*)d_ws;                 // 25600 halves
    _Float16* W2h = (_Float16*)d_ws + W1H_HALVES;    // 102400 halves

    const int cvt_dwords = (W1H_HALVES + W2H_HALVES) / 2;      // 64000
    cvt_kernel<<<(cvt_dwords + 255) / 256, 256, 0, stream>>>(
        W1, W2, (unsigned int*)d_ws);

    feat_kernel<<<64 * NATOM, 256, 0, stream>>>(
        coords, types, W0, B0, B1, B2, W1h, W2h, out);
}